// Round 17
// baseline (2382.491 us; speedup 1.0000x reference)
//
#include <hip/hip_runtime.h>
#include <stdint.h>

// FFJORD block: B=2048, D=512, H=1024, 9 RK38 steps x 4 stages, 2 Hutchinson probes.
// f32 in/out. bf16 MFMA GEMMs, f32 accumulate, fp32 RK state.
// PRNG: JAX threefry partitionable (verified R7).
// R17 = R14 base (best: 1401us) + e-fragments expanded from PACKED BITS in
// registers (1 uint4/(row,probe)/4iters + ~27 VALU per frag, sign-bit trick).
// f1 LDS reads 10->6 per wave-iter, DMA 20->12KB. Packed bits (512KB ring)
// generated in f3 epilogue (16 tf-evals/thread); stage 0 seeded separately.
// XCD affinity (R14) + LDS swizzle (R13) kept.

#define B_N 2048
#define D_N 512
#define H_N 1024
#define BD (B_N * D_N)

typedef unsigned short u16;
typedef __attribute__((ext_vector_type(8))) short s16x8;   // 8 x bf16
typedef __attribute__((ext_vector_type(4))) float f32x4;   // MFMA accumulator

typedef __attribute__((address_space(1))) const uint32_t ga_u32;
typedef __attribute__((address_space(3))) uint32_t ls_u32;

#if __has_builtin(__builtin_amdgcn_alignbit)
#define ROTL32(x, r) __builtin_amdgcn_alignbit((x), (x), 32 - (r))
#else
#define ROTL32(x, r) (((x) << (r)) | ((x) >> (32 - (r))))
#endif

__device__ __forceinline__ u16 f2bf(float f) {
  union { float f; uint32_t u; } c; c.f = f;
  uint32_t r = c.u + 0x7FFFu + ((c.u >> 16) & 1u);  // RTNE
  return (u16)(r >> 16);
}
__device__ __forceinline__ float fast_tanh(float v) {
  float e = __expf(2.0f * fabsf(v));
  float t = 1.0f - 2.0f / (e + 1.0f);
  return copysignf(t, v);
}

struct U2 { uint32_t x, y; };

// Threefry-2x32, 20 rounds — KAT-verified.
__device__ __forceinline__ U2 tf2x32(uint32_t k0, uint32_t k1, uint32_t x0, uint32_t x1) {
  uint32_t k2 = k0 ^ k1 ^ 0x1BD11BDAu;
#define RND(r) { x0 += x1; x1 = ROTL32(x1, r); x1 ^= x0; }
  x0 += k0; x1 += k1;
  RND(13) RND(15) RND(26) RND(6)
  x0 += k1; x1 += k2 + 1u;
  RND(17) RND(29) RND(16) RND(24)
  x0 += k2; x1 += k0 + 2u;
  RND(13) RND(15) RND(26) RND(6)
  x0 += k0; x1 += k1 + 3u;
  RND(17) RND(29) RND(16) RND(24)
  x0 += k1; x1 += k2 + 4u;
  RND(13) RND(15) RND(26) RND(6)
  x0 += k2; x1 += k0 + 5u;
#undef RND
  U2 r; r.x = x0; r.y = x1; return r;
}

// Partitionable key schedule (verified R7).
__global__ void k_keysched(uint32_t* __restrict__ ekeys) {
  if (threadIdx.x != 0 || blockIdx.x != 0) return;
  uint32_t kx = 0u, ky = 1234u;
  for (int s = 0; s < 9; ++s) {
    for (int st = 0; st < 4; ++st) {
      U2 kst = tf2x32(kx, ky, 0u, (uint32_t)(st + 1));
      for (int pr = 0; pr < 2; ++pr) {
        U2 fo = tf2x32(kst.x, kst.y, 0u, (uint32_t)pr);
        U2 k2 = tf2x32(fo.x, fo.y, 0u, 1u);
        ekeys[(s * 4 + st) * 4 + pr * 2 + 0] = k2.x;
        ekeys[(s * 4 + st) * 4 + pr * 2 + 1] = k2.y;
      }
    }
    U2 c = tf2x32(kx, ky, 0u, 0u);
    kx = c.x; ky = c.y;
  }
}

// Stage-0 packed bits into ring slot 0: dword d covers p in [d*32, d*32+32);
// bit = lsb(x^y) of tf(k2,(0,p)). Layout: [probe][32768 dwords].
__global__ void k_ebits1(uint32_t* __restrict__ eb, const uint32_t* __restrict__ keys) {
  int t = blockIdx.x * 256 + threadIdx.x;   // 65536 threads, one dword each
  int probe = t >> 15, d = t & 32767;
  uint32_t p0 = (uint32_t)d * 32;
  uint32_t k0 = keys[probe * 2], k1 = keys[probe * 2 + 1];
  uint32_t bits = 0;
#pragma unroll 4
  for (int j = 0; j < 32; ++j) {
    U2 r = tf2x32(k0, k1, 0u, p0 + j);
    bits |= ((r.x ^ r.y) & 1u) << j;
  }
  eb[probe * 32768 + d] = bits;
}

__global__ void k_init(const float* __restrict__ x, float* __restrict__ z, u16* __restrict__ zin,
                       float* __restrict__ lp, float* __restrict__ d0, float* __restrict__ d1) {
  int i = blockIdx.x * 256 + threadIdx.x;
  if (i < BD) { float v = x[i]; z[i] = v; zin[i] = f2bf(v); }
  if (i < B_N) { lp[i] = 0.f; d0[i] = 0.f; d1[i] = 0.f; }
}

__global__ void k_cvtT(const float* __restrict__ src, u16* __restrict__ dst, int R, int C) {
  int i = blockIdx.x * 256 + threadIdx.x;
  if (i >= R * C) return;
  int c = i / R, r = i - c * R;
  dst[i] = f2bf(src[(size_t)r * C + c]);
}
__global__ void k_cvt(const float* __restrict__ src, u16* __restrict__ dst, int n) {
  int i = blockIdx.x * 256 + threadIdx.x;
  if (i < n) dst[i] = f2bf(src[i]);
}

__global__ void k_sentinel(float* __restrict__ out, int n) {
  int i = blockIdx.x * 256 + threadIdx.x;
  if (i < n) out[i] = 12345.0f;
}

// Expand byte (8 e-bits) -> s16x8 of +-1 bf16. bit=1 -> +1 (0x3F80), 0 -> -1.
__device__ __forceinline__ s16x8 expand8(uint32_t byteval) {
  union { s16x8 v; uint32_t d[4]; } f;
  uint32_t sb = byteval ^ 0xFFu;   // sign bits
#pragma unroll
  for (int d2 = 0; d2 < 4; ++d2) {
    uint32_t t = sb >> (2 * d2);
    f.d[d2] = 0x3F803F80u | ((t & 1u) << 15) | ((t & 2u) << 30);
  }
  return f.v;
}

// Fused 5-product GEMM, 64x64 tiles, K=512, 256 thr (2x2 waves). zin/W1/W2 via
// dbuf DMA (12KB/buf, R13 swizzle); e expanded from packed bits in registers.
__global__ __launch_bounds__(256)
void k_f1(const u16* __restrict__ zin, const uint32_t* __restrict__ ebits,
          const u16* __restrict__ W1T, const u16* __restrict__ W2b,
          const float* __restrict__ b1v, const float* __restrict__ tw1v, float tstage,
          u16* __restrict__ hbuf, float* __restrict__ div0, float* __restrict__ div1) {
  __shared__ u16 S[2][3 * 2048];
  const int tid = threadIdx.x, wave = tid >> 6, lane = tid & 63;
  const int xcd = blockIdx.x & 7, idx = blockIdx.x >> 3;
  const int bm = xcd * 4 + (idx >> 4);       // slab pinned to XCD
  const int bh = idx & 15;
  const int row0 = bm * 64, col0 = bh * 64;
  const int wm = wave >> 1, wn = wave & 1, r16 = lane & 15, q = lane >> 4;
  const int srow = lane >> 2;
  const int scol = (((lane & 3) ^ ((srow >> 1) & 3))) * 8;   // swizzled source chunk
  const int cqa = (q ^ ((r16 >> 1) & 3)) * 8;                // swizzled read chunk

  f32x4 az[2][2], au0[2][2], au1[2][2], av0[2][2], av1[2][2];
#pragma unroll
  for (int i = 0; i < 2; ++i)
#pragma unroll
    for (int j = 0; j < 2; ++j) {
      az[i][j] = (f32x4){0,0,0,0}; au0[i][j] = (f32x4){0,0,0,0}; au1[i][j] = (f32x4){0,0,0,0};
      av0[i][j] = (f32x4){0,0,0,0}; av1[i][j] = (f32x4){0,0,0,0};
    }

  const size_t arow = (size_t)(row0 + srow) * 512 + scol;    // zin rows (per-chunk offset added)
  const size_t brow = (size_t)(col0 + srow) * 512 + scol;
  auto stage = [&](int kt, int buf) {
    u16* b = &S[buf][0];
#pragma unroll
    for (int c = wave; c < 12; c += 4) {       // 3 arrays x 4 row-chunks
      const int arr = c >> 2, ch = c & 3;
      const size_t off = (arr == 0 ? arow : brow) + (size_t)(ch * 16) * 512 + kt;
      const u16* src = (arr == 0 ? zin : arr == 1 ? W1T : W2b) + off;
      __builtin_amdgcn_global_load_lds((ga_u32*)src, (ls_u32*)(b + arr * 2048 + ch * 512), 16, 0, 0);
    }
  };

  // e packed-bit pipeline: per (row i, probe pr) one uint4 covers 4 K-iters.
  const int r0i = row0 + wm * 32 + r16;        // row for i=0 (i=1: +16)
  uint4 ebq[2][2], ebn[2][2];
#pragma unroll
  for (int i = 0; i < 2; ++i)
#pragma unroll
    for (int pr = 0; pr < 2; ++pr)
      ebn[i][pr] = *(const uint4*)(ebits + pr * 32768 + (r0i + i * 16) * 16);

  stage(0, 0);
#pragma unroll
  for (int it = 0; it < 16; ++it) {
    const int buf = it & 1;
    if ((it & 3) == 0) {
#pragma unroll
      for (int i = 0; i < 2; ++i)
#pragma unroll
        for (int pr = 0; pr < 2; ++pr) ebq[i][pr] = ebn[i][pr];
      if (it + 4 < 16) {
#pragma unroll
        for (int i = 0; i < 2; ++i)
#pragma unroll
          for (int pr = 0; pr < 2; ++pr)
            ebn[i][pr] = *(const uint4*)(ebits + pr * 32768 + (r0i + i * 16) * 16 + it + 4);
      }
    }
    __syncthreads();
    if (it + 1 < 16) stage((it + 1) * 32, buf ^ 1);
    const u16* b = &S[buf][0];
    s16x8 zf[2], e0f[2], e1f[2], w1f[2], w2f[2];
#pragma unroll
    for (int i = 0; i < 2; ++i) {
      zf[i] = *(const s16x8*)(b + (wm * 32 + i * 16 + r16) * 32 + cqa);
      const uint32_t d0w = (it & 3) == 0 ? ebq[i][0].x : (it & 3) == 1 ? ebq[i][0].y
                         : (it & 3) == 2 ? ebq[i][0].z : ebq[i][0].w;
      const uint32_t d1w = (it & 3) == 0 ? ebq[i][1].x : (it & 3) == 1 ? ebq[i][1].y
                         : (it & 3) == 2 ? ebq[i][1].z : ebq[i][1].w;
      e0f[i] = expand8((d0w >> (q * 8)) & 0xFFu);
      e1f[i] = expand8((d1w >> (q * 8)) & 0xFFu);
    }
#pragma unroll
    for (int j = 0; j < 2; ++j) {
      const int bo = (wn * 32 + j * 16 + r16) * 32 + cqa;
      w1f[j] = *(const s16x8*)(b + 2048 + bo);
      w2f[j] = *(const s16x8*)(b + 4096 + bo);
    }
#pragma unroll
    for (int i = 0; i < 2; ++i)
#pragma unroll
      for (int j = 0; j < 2; ++j) {
        az[i][j]  = __builtin_amdgcn_mfma_f32_16x16x32_bf16(zf[i],  w1f[j], az[i][j],  0, 0, 0);
        au0[i][j] = __builtin_amdgcn_mfma_f32_16x16x32_bf16(e0f[i], w1f[j], au0[i][j], 0, 0, 0);
        au1[i][j] = __builtin_amdgcn_mfma_f32_16x16x32_bf16(e1f[i], w1f[j], au1[i][j], 0, 0, 0);
        av0[i][j] = __builtin_amdgcn_mfma_f32_16x16x32_bf16(e0f[i], w2f[j], av0[i][j], 0, 0, 0);
        av1[i][j] = __builtin_amdgcn_mfma_f32_16x16x32_bf16(e1f[i], w2f[j], av1[i][j], 0, 0, 0);
      }
  }

  float d0s[2][4], d1s[2][4];
#pragma unroll
  for (int i = 0; i < 2; ++i)
#pragma unroll
    for (int r = 0; r < 4; ++r) { d0s[i][r] = 0.f; d1s[i][r] = 0.f; }

#pragma unroll
  for (int j = 0; j < 2; ++j) {
    const int gcol = col0 + wn * 32 + j * 16 + r16;
    const float colb = b1v[gcol] + tstage * tw1v[gcol];
#pragma unroll
    for (int i = 0; i < 2; ++i) {
      const int rbase = row0 + wm * 32 + i * 16 + q * 4;   // C/D: row=quad*4+reg
#pragma unroll
      for (int r = 0; r < 4; ++r) {
        float hv = fast_tanh(az[i][j][r] + colb);
        hbuf[(size_t)(rbase + r) * H_N + gcol] = f2bf(hv);
        float s = 1.f - hv * hv;
        d0s[i][r] += s * au0[i][j][r] * av0[i][j][r];
        d1s[i][r] += s * au1[i][j][r] * av1[i][j][r];
      }
    }
  }
#pragma unroll
  for (int i = 0; i < 2; ++i)
#pragma unroll
    for (int r = 0; r < 4; ++r) {
      float a = d0s[i][r], bb = d1s[i][r];
#pragma unroll
      for (int m = 1; m < 16; m <<= 1) { a += __shfl_xor(a, m); bb += __shfl_xor(bb, m); }
      if (r16 == 0) {
        int grow = row0 + wm * 32 + i * 16 + q * 4 + r;
        atomicAdd(&div0[grow], a);
        atomicAdd(&div1[grow], bb);
      }
    }
}

// GEMM3 (f = h@W2 + b2), 64x32 tiles (512 blocks), K=1024; RK38 epilogue +
// fused divapply (bn==0) + NEXT stage packed e-bits (16 tf-evals/thread).
template<int ST>
__global__ __launch_bounds__(256)
void k_f3(const u16* __restrict__ hbuf, const u16* __restrict__ W2T, const float* __restrict__ b2v,
          float* __restrict__ z, float* __restrict__ ACC, float* __restrict__ T,
          u16* __restrict__ zin, float dt,
          float* __restrict__ lp, float* __restrict__ div0, float* __restrict__ div1, float wdt,
          const uint32_t* __restrict__ keys, int sg, uint32_t* __restrict__ ebnext) {
  __shared__ u16 S[2][3 * 2048];
  const int tid = threadIdx.x, wave = tid >> 6, lane = tid & 63;
  const int xcd = blockIdx.x & 7, idx = blockIdx.x >> 3;
  const int bm = xcd * 4 + (idx >> 4);       // slab pinned to XCD (matches f1)
  const int bn = idx & 15;
  const int row0 = bm * 64, col0 = bn * 32;
  const int r16 = lane & 15, q = lane >> 4;
  const int srow = lane >> 2;
  const int scol = (((lane & 3) ^ ((srow >> 1) & 3))) * 8;
  const int cqa = (q ^ ((r16 >> 1) & 3)) * 8;

  if (bn == 0 && tid < 64) {
    int b = row0 + tid;
    float c = 0.5f * (div0[b] + div1[b]);
    c = fminf(fmaxf(c, -100.f), 100.f);
    lp[b] -= wdt * c;
    div0[b] = 0.f; div1[b] = 0.f;
  }

  f32x4 acc[2];
  acc[0] = (f32x4){0,0,0,0}; acc[1] = (f32x4){0,0,0,0};

  const size_t arow = (size_t)(row0 + wave * 16 + srow) * 1024 + scol;
  const size_t brow = (size_t)(col0 + (wave & 1) * 16 + srow) * 1024 + scol;
  auto stage = [&](int kt, int buf) {
    u16* b = &S[buf][0];
    __builtin_amdgcn_global_load_lds((ga_u32*)(hbuf + arow + kt), (ls_u32*)(b + wave * 512), 16, 0, 0);
    if (wave < 2)
      __builtin_amdgcn_global_load_lds((ga_u32*)(W2T + brow + kt), (ls_u32*)(b + 4096 + wave * 512), 16, 0, 0);
  };
  stage(0, 0);
  for (int it = 0; it < 32; ++it) {
    const int buf = it & 1;
    __syncthreads();
    if (it + 1 < 32) stage((it + 1) * 32, buf ^ 1);
    const u16* b = &S[buf][0];
    s16x8 af  = *(const s16x8*)(b + (wave * 16 + r16) * 32 + cqa);
    s16x8 bf0 = *(const s16x8*)(b + 4096 + r16 * 32 + cqa);
    s16x8 bf1 = *(const s16x8*)(b + 4096 + (16 + r16) * 32 + cqa);
    acc[0] = __builtin_amdgcn_mfma_f32_16x16x32_bf16(af, bf0, acc[0], 0, 0, 0);
    acc[1] = __builtin_amdgcn_mfma_f32_16x16x32_bf16(af, bf1, acc[1], 0, 0, 0);
  }

#pragma unroll
  for (int j = 0; j < 2; ++j) {
    const int gcol = col0 + j * 16 + r16;
    const float cb = b2v[gcol];
    const int rbase = row0 + wave * 16 + q * 4;
#pragma unroll
    for (int r = 0; r < 4; ++r) {
      const size_t idx2 = (size_t)(rbase + r) * D_N + gcol;
      const float f = acc[j][r] + cb;
      if (ST == 0) {
        ACC[idx2] = dt * 0.125f * f;
        T[idx2]   = dt * f;
        zin[idx2] = f2bf(z[idx2] + dt * f * (1.f / 3.f));
      } else if (ST == 1) {
        float t_ = T[idx2];
        ACC[idx2] += 0.375f * dt * f;
        zin[idx2] = f2bf(z[idx2] + dt * f - t_ * (1.f / 3.f));
        T[idx2]   = t_ - dt * f;
      } else if (ST == 2) {
        ACC[idx2] += 0.375f * dt * f;
        zin[idx2] = f2bf(z[idx2] + T[idx2] + dt * f);
      } else {
        float zn = z[idx2] + ACC[idx2] + dt * 0.125f * f;
        z[idx2]   = zn;
        zin[idx2] = f2bf(zn);
      }
    }
  }

  // Packed e-bits for stage sg+1, this block's 128 dwords (2 probes x 64).
  if (ebnext) {
    const int pr = tid >> 7, u = tid & 127;
    const int d = bm * 1024 + bn * 64 + (u >> 1);    // dword index within probe
    const int half = u & 1;
    const uint32_t k0 = keys[(sg + 1) * 4 + pr * 2], k1 = keys[(sg + 1) * 4 + pr * 2 + 1];
    const uint32_t p0 = (uint32_t)d * 32 + half * 16;
    uint32_t bits = 0;
#pragma unroll 4
    for (int j = 0; j < 16; ++j) {
      U2 r = tf2x32(k0, k1, 0u, p0 + j);
      bits |= ((r.x ^ r.y) & 1u) << j;
    }
    uint32_t other = __shfl_xor(bits, 1);
    if (half == 0) ebnext[pr * 32768 + d] = bits | (other << 16);
  }
}

// out = [rep (f32, BxD) ; logprob (f32, B)] — XCD-affine row mapping.
__global__ void k_out(const float* __restrict__ z, const float* __restrict__ lp,
                      float* __restrict__ out) {
  const int xcd = blockIdx.x & 7, idx = blockIdx.x >> 3;    // 2048 blocks
  const int b = (xcd * 4 + (idx >> 6)) * 64 + (idx & 63);
  int t = threadIdx.x;
  const float* zr = z + (size_t)b * D_N;
  float ss = 0.f;
  for (int d = t; d < D_N; d += 256) {
    float v = zr[d];
    out[(size_t)b * D_N + d] = v;
    ss += v * v;
  }
  for (int off = 32; off > 0; off >>= 1) ss += __shfl_down(ss, off);
  __shared__ float red[4];
  if ((t & 63) == 0) red[t >> 6] = ss;
  __syncthreads();
  if (t == 0) out[(size_t)BD + b] = -0.5f * (red[0] + red[1] + red[2] + red[3]) + lp[b];
}

extern "C" void kernel_launch(void* const* d_in, const int* in_sizes, int n_in,
                              void* d_out, int out_size, void* d_ws, size_t ws_size,
                              hipStream_t stream) {
  const float* x   = (const float*)d_in[0];
  const float* W1  = (const float*)d_in[1];
  const float* b1  = (const float*)d_in[2];
  const float* tw1 = (const float*)d_in[3];
  const float* W2  = (const float*)d_in[4];
  const float* b2  = (const float*)d_in[5];
  float* outp = (float*)d_out;

  const size_t NEEDED = (size_t)35 << 20;
  if (ws_size < NEEDED) {
    k_sentinel<<<(BD + B_N + 255) / 256, 256, 0, stream>>>(outp, BD + B_N);
    return;
  }
  char* w = (char*)d_ws;
  auto carve = [&](size_t bytes) { char* p = w; w += (bytes + 255) & ~(size_t)255; return p; };
  uint32_t* keys  = (uint32_t*)carve(144 * sizeof(uint32_t));
  uint32_t* ebits = (uint32_t*)carve((size_t)2 * 65536 * 4);      // 512 KB: 2-slot packed ring
  float* z   = (float*)carve((size_t)BD * 4);
  float* ACC = (float*)carve((size_t)BD * 4);
  float* T   = (float*)carve((size_t)BD * 4);
  u16* zin   = (u16*)carve((size_t)BD * 2);
  u16* hbuf  = (u16*)carve((size_t)B_N * H_N * 2);
  u16* W1T   = (u16*)carve((size_t)H_N * D_N * 2);
  u16* W2b   = (u16*)carve((size_t)H_N * D_N * 2);
  u16* W2T   = (u16*)carve((size_t)D_N * H_N * 2);
  float* lp   = (float*)carve((size_t)B_N * 4);
  float* div0 = (float*)carve((size_t)B_N * 4);
  float* div1 = (float*)carve((size_t)B_N * 4);

  k_keysched<<<1, 1, 0, stream>>>(keys);
  k_ebits1<<<256, 256, 0, stream>>>(ebits, keys);   // stage 0 -> slot 0
  k_init<<<BD / 256, 256, 0, stream>>>(x, z, zin, lp, div0, div1);
  k_cvtT<<<(D_N * H_N) / 256, 256, 0, stream>>>(W1, W1T, D_N, H_N);
  k_cvt <<<(H_N * D_N) / 256, 256, 0, stream>>>(W2, W2b, H_N * D_N);
  k_cvtT<<<(H_N * D_N) / 256, 256, 0, stream>>>(W2, W2T, H_N, D_N);

  const int gF1 = (B_N / 64) * (H_N / 64);   // 512
  const int gF3 = (B_N / 64) * (D_N / 32);   // 512

  for (int s = 0; s < 9; ++s) {
    float t0 = (float)s / 9.0f;
    float t1 = (float)(s + 1) / 9.0f;
    float dt = t1 - t0;
    float tst[4] = { t0, t0 + dt / 3.0f, t0 + dt * 2.0f / 3.0f, t1 };
    float wts[4] = { 1.f, 3.f, 3.f, 1.f };
    for (int st = 0; st < 4; ++st) {
      const int sg = s * 4 + st;
      const uint32_t* eslot = ebits + (size_t)(sg & 1) * 65536;
      uint32_t* enext = (sg + 1 < 36) ? ebits + (size_t)((sg + 1) & 1) * 65536 : nullptr;
      k_f1<<<gF1, 256, 0, stream>>>(zin, eslot, W1T, W2b, b1, tw1, tst[st], hbuf, div0, div1);
      const float wdt = dt * 0.125f * wts[st];
      if (st == 0)      k_f3<0><<<gF3, 256, 0, stream>>>(hbuf, W2T, b2, z, ACC, T, zin, dt, lp, div0, div1, wdt, keys, sg, enext);
      else if (st == 1) k_f3<1><<<gF3, 256, 0, stream>>>(hbuf, W2T, b2, z, ACC, T, zin, dt, lp, div0, div1, wdt, keys, sg, enext);
      else if (st == 2) k_f3<2><<<gF3, 256, 0, stream>>>(hbuf, W2T, b2, z, ACC, T, zin, dt, lp, div0, div1, wdt, keys, sg, enext);
      else              k_f3<3><<<gF3, 256, 0, stream>>>(hbuf, W2T, b2, z, ACC, T, zin, dt, lp, div0, div1, wdt, keys, sg, enext);
    }
  }
  k_out<<<B_N, 256, 0, stream>>>(z, lp, outp);
}

// Round 18
// 1405.825 us; speedup vs baseline: 1.6947x; 1.6947x over previous
//
#include <hip/hip_runtime.h>
#include <stdint.h>

// FFJORD block: B=2048, D=512, H=1024, 9 RK38 steps x 4 stages, 2 Hutchinson probes.
// f32 in/out. bf16 MFMA GEMMs, f32 accumulate, fp32 RK state.
// PRNG: JAX threefry partitionable (verified R7).
// R18 = R14 verbatim (best: 1401us; A-tiles via global_load_lds DMA — R15/R17
// scattered-load variants regressed) + egen folded into f3 epilogue (2-slot
// bf16 e-ring, stage-0 seeded once) — removes 9 k_egen launches.
// XCD affinity (R14) + LDS swizzle (R13) kept.

#define B_N 2048
#define D_N 512
#define H_N 1024
#define BD (B_N * D_N)

typedef unsigned short u16;
typedef __attribute__((ext_vector_type(8))) short s16x8;   // 8 x bf16
typedef __attribute__((ext_vector_type(4))) float f32x4;   // MFMA accumulator

typedef __attribute__((address_space(1))) const uint32_t ga_u32;
typedef __attribute__((address_space(3))) uint32_t ls_u32;

#if __has_builtin(__builtin_amdgcn_alignbit)
#define ROTL32(x, r) __builtin_amdgcn_alignbit((x), (x), 32 - (r))
#else
#define ROTL32(x, r) (((x) << (r)) | ((x) >> (32 - (r))))
#endif

__device__ __forceinline__ u16 f2bf(float f) {
  union { float f; uint32_t u; } c; c.f = f;
  uint32_t r = c.u + 0x7FFFu + ((c.u >> 16) & 1u);  // RTNE
  return (u16)(r >> 16);
}
__device__ __forceinline__ float fast_tanh(float v) {
  float e = __expf(2.0f * fabsf(v));
  float t = 1.0f - 2.0f / (e + 1.0f);
  return copysignf(t, v);
}

struct U2 { uint32_t x, y; };

// Threefry-2x32, 20 rounds — KAT-verified.
__device__ __forceinline__ U2 tf2x32(uint32_t k0, uint32_t k1, uint32_t x0, uint32_t x1) {
  uint32_t k2 = k0 ^ k1 ^ 0x1BD11BDAu;
#define RND(r) { x0 += x1; x1 = ROTL32(x1, r); x1 ^= x0; }
  x0 += k0; x1 += k1;
  RND(13) RND(15) RND(26) RND(6)
  x0 += k1; x1 += k2 + 1u;
  RND(17) RND(29) RND(16) RND(24)
  x0 += k2; x1 += k0 + 2u;
  RND(13) RND(15) RND(26) RND(6)
  x0 += k0; x1 += k1 + 3u;
  RND(17) RND(29) RND(16) RND(24)
  x0 += k1; x1 += k2 + 4u;
  RND(13) RND(15) RND(26) RND(6)
  x0 += k2; x1 += k0 + 5u;
#undef RND
  U2 r; r.x = x0; r.y = x1; return r;
}

// Partitionable key schedule (verified R7).
__global__ void k_keysched(uint32_t* __restrict__ ekeys) {
  if (threadIdx.x != 0 || blockIdx.x != 0) return;
  uint32_t kx = 0u, ky = 1234u;
  for (int s = 0; s < 9; ++s) {
    for (int st = 0; st < 4; ++st) {
      U2 kst = tf2x32(kx, ky, 0u, (uint32_t)(st + 1));
      for (int pr = 0; pr < 2; ++pr) {
        U2 fo = tf2x32(kst.x, kst.y, 0u, (uint32_t)pr);
        U2 k2 = tf2x32(fo.x, fo.y, 0u, 1u);
        ekeys[(s * 4 + st) * 4 + pr * 2 + 0] = k2.x;
        ekeys[(s * 4 + st) * 4 + pr * 2 + 1] = k2.y;
      }
    }
    U2 c = tf2x32(kx, ky, 0u, 0u);
    kx = c.x; ky = c.y;
  }
}

// Stage-0 bf16 e into ring slot 0. e_p = lsb(x^y) of tf(k2, (0,p)).
__global__ void k_egen1(u16* __restrict__ ebf, const uint32_t* __restrict__ keys) {
  int t = blockIdx.x * 256 + threadIdx.x;   // 65536 threads, 32 elems each
  int probe = t >> 15, idx = t & 32767;
  uint32_t p0 = (uint32_t)idx * 32;
  uint32_t k0 = keys[probe * 2], k1 = keys[probe * 2 + 1];
  uint4* dst = (uint4*)(ebf + (size_t)probe * BD + (size_t)p0);
#pragma unroll
  for (int g = 0; g < 4; ++g) {
    uint32_t pr[4];
#pragma unroll
    for (int h = 0; h < 4; ++h) {
      uint32_t c0 = p0 + g * 8 + h * 2;
      U2 r0 = tf2x32(k0, k1, 0u, c0);
      U2 r1 = tf2x32(k0, k1, 0u, c0 + 1u);
      pr[h] = (((r0.x ^ r0.y) & 1u) ? 0x3F80u : 0xBF80u) |
              (((r1.x ^ r1.y) & 1u) ? 0x3F800000u : 0xBF800000u);
    }
    uint4 v; v.x = pr[0]; v.y = pr[1]; v.z = pr[2]; v.w = pr[3];
    dst[g] = v;
  }
}

__global__ void k_init(const float* __restrict__ x, float* __restrict__ z, u16* __restrict__ zin,
                       float* __restrict__ lp, float* __restrict__ d0, float* __restrict__ d1) {
  int i = blockIdx.x * 256 + threadIdx.x;
  if (i < BD) { float v = x[i]; z[i] = v; zin[i] = f2bf(v); }
  if (i < B_N) { lp[i] = 0.f; d0[i] = 0.f; d1[i] = 0.f; }
}

__global__ void k_cvtT(const float* __restrict__ src, u16* __restrict__ dst, int R, int C) {
  int i = blockIdx.x * 256 + threadIdx.x;
  if (i >= R * C) return;
  int c = i / R, r = i - c * R;
  dst[i] = f2bf(src[(size_t)r * C + c]);
}
__global__ void k_cvt(const float* __restrict__ src, u16* __restrict__ dst, int n) {
  int i = blockIdx.x * 256 + threadIdx.x;
  if (i < n) dst[i] = f2bf(src[i]);
}

__global__ void k_sentinel(float* __restrict__ out, int n) {
  int i = blockIdx.x * 256 + threadIdx.x;
  if (i < n) out[i] = 12345.0f;
}

// LDS chunk swizzle (R13): data chunk c of row r at LDS chunk c^((r>>1)&3).

// Fused 5-product GEMM, 64x64 tiles, K=512. XCD-affine slab; dbuf DMA; swizzle.
__global__ __launch_bounds__(256)
void k_f1(const u16* __restrict__ zin, const u16* __restrict__ e0g, const u16* __restrict__ e1g,
          const u16* __restrict__ W1T, const u16* __restrict__ W2b,
          const float* __restrict__ b1v, const float* __restrict__ tw1v, float tstage,
          u16* __restrict__ hbuf, float* __restrict__ div0, float* __restrict__ div1) {
  __shared__ u16 S[2][5 * 2048];
  const int tid = threadIdx.x, wave = tid >> 6, lane = tid & 63;
  const int xcd = blockIdx.x & 7, idx = blockIdx.x >> 3;
  const int bm = xcd * 4 + (idx >> 4);       // slab pinned to XCD
  const int bh = idx & 15;
  const int row0 = bm * 64, col0 = bh * 64;
  const int wm = wave >> 1, wn = wave & 1, r16 = lane & 15, q = lane >> 4;
  const int srow = lane >> 2;
  const int scol = (((lane & 3) ^ ((srow >> 1) & 3))) * 8;   // swizzled source chunk
  const int cqa = (q ^ ((r16 >> 1) & 3)) * 8;                // swizzled read chunk

  f32x4 az[2][2], au0[2][2], au1[2][2], av0[2][2], av1[2][2];
#pragma unroll
  for (int i = 0; i < 2; ++i)
#pragma unroll
    for (int j = 0; j < 2; ++j) {
      az[i][j] = (f32x4){0,0,0,0}; au0[i][j] = (f32x4){0,0,0,0}; au1[i][j] = (f32x4){0,0,0,0};
      av0[i][j] = (f32x4){0,0,0,0}; av1[i][j] = (f32x4){0,0,0,0};
    }

  const size_t arow = (size_t)(row0 + wave * 16 + srow) * 512 + scol;
  const size_t brow = (size_t)(col0 + wave * 16 + srow) * 512 + scol;
  auto stage = [&](int kt, int buf) {
    u16* b = &S[buf][0];
    __builtin_amdgcn_global_load_lds((ga_u32*)(zin + arow + kt), (ls_u32*)(b + 0    + wave * 512), 16, 0, 0);
    __builtin_amdgcn_global_load_lds((ga_u32*)(e0g + arow + kt), (ls_u32*)(b + 2048 + wave * 512), 16, 0, 0);
    __builtin_amdgcn_global_load_lds((ga_u32*)(e1g + arow + kt), (ls_u32*)(b + 4096 + wave * 512), 16, 0, 0);
    __builtin_amdgcn_global_load_lds((ga_u32*)(W1T + brow + kt), (ls_u32*)(b + 6144 + wave * 512), 16, 0, 0);
    __builtin_amdgcn_global_load_lds((ga_u32*)(W2b + brow + kt), (ls_u32*)(b + 8192 + wave * 512), 16, 0, 0);
  };
  stage(0, 0);
  for (int it = 0; it < 16; ++it) {
    const int buf = it & 1;
    __syncthreads();
    if (it + 1 < 16) stage((it + 1) * 32, buf ^ 1);
    const u16* b = &S[buf][0];
    s16x8 zf[2], e0f[2], e1f[2], w1f[2], w2f[2];
#pragma unroll
    for (int i = 0; i < 2; ++i) {
      const int ao = (wm * 32 + i * 16 + r16) * 32 + cqa;
      zf[i]  = *(const s16x8*)(b + 0    + ao);
      e0f[i] = *(const s16x8*)(b + 2048 + ao);
      e1f[i] = *(const s16x8*)(b + 4096 + ao);
    }
#pragma unroll
    for (int j = 0; j < 2; ++j) {
      const int bo = (wn * 32 + j * 16 + r16) * 32 + cqa;
      w1f[j] = *(const s16x8*)(b + 6144 + bo);
      w2f[j] = *(const s16x8*)(b + 8192 + bo);
    }
#pragma unroll
    for (int i = 0; i < 2; ++i)
#pragma unroll
      for (int j = 0; j < 2; ++j) {
        az[i][j]  = __builtin_amdgcn_mfma_f32_16x16x32_bf16(zf[i],  w1f[j], az[i][j],  0, 0, 0);
        au0[i][j] = __builtin_amdgcn_mfma_f32_16x16x32_bf16(e0f[i], w1f[j], au0[i][j], 0, 0, 0);
        au1[i][j] = __builtin_amdgcn_mfma_f32_16x16x32_bf16(e1f[i], w1f[j], au1[i][j], 0, 0, 0);
        av0[i][j] = __builtin_amdgcn_mfma_f32_16x16x32_bf16(e0f[i], w2f[j], av0[i][j], 0, 0, 0);
        av1[i][j] = __builtin_amdgcn_mfma_f32_16x16x32_bf16(e1f[i], w2f[j], av1[i][j], 0, 0, 0);
      }
  }

  float d0s[2][4], d1s[2][4];
#pragma unroll
  for (int i = 0; i < 2; ++i)
#pragma unroll
    for (int r = 0; r < 4; ++r) { d0s[i][r] = 0.f; d1s[i][r] = 0.f; }

#pragma unroll
  for (int j = 0; j < 2; ++j) {
    const int gcol = col0 + wn * 32 + j * 16 + r16;
    const float colb = b1v[gcol] + tstage * tw1v[gcol];
#pragma unroll
    for (int i = 0; i < 2; ++i) {
      const int rbase = row0 + wm * 32 + i * 16 + q * 4;   // C/D: row=quad*4+reg
#pragma unroll
      for (int r = 0; r < 4; ++r) {
        float hv = fast_tanh(az[i][j][r] + colb);
        hbuf[(size_t)(rbase + r) * H_N + gcol] = f2bf(hv);
        float s = 1.f - hv * hv;
        d0s[i][r] += s * au0[i][j][r] * av0[i][j][r];
        d1s[i][r] += s * au1[i][j][r] * av1[i][j][r];
      }
    }
  }
#pragma unroll
  for (int i = 0; i < 2; ++i)
#pragma unroll
    for (int r = 0; r < 4; ++r) {
      float a = d0s[i][r], bb = d1s[i][r];
#pragma unroll
      for (int m = 1; m < 16; m <<= 1) { a += __shfl_xor(a, m); bb += __shfl_xor(bb, m); }
      if (r16 == 0) {
        int grow = row0 + wm * 32 + i * 16 + q * 4 + r;
        atomicAdd(&div0[grow], a);
        atomicAdd(&div1[grow], bb);
      }
    }
}

// GEMM3 (f = h@W2 + b2), 64x32 tiles (512 blocks), K=1024; RK38 epilogue +
// fused divapply (bn==0) + NEXT stage's bf16 e-gen (2-slot ring). XCD-affine.
template<int ST>
__global__ __launch_bounds__(256)
void k_f3(const u16* __restrict__ hbuf, const u16* __restrict__ W2T, const float* __restrict__ b2v,
          float* __restrict__ z, float* __restrict__ ACC, float* __restrict__ T,
          u16* __restrict__ zin, float dt,
          float* __restrict__ lp, float* __restrict__ div0, float* __restrict__ div1, float wdt,
          const uint32_t* __restrict__ keys, int sg, u16* __restrict__ ebfnext) {
  __shared__ u16 S[2][3 * 2048];
  const int tid = threadIdx.x, wave = tid >> 6, lane = tid & 63;
  const int xcd = blockIdx.x & 7, idx = blockIdx.x >> 3;
  const int bm = xcd * 4 + (idx >> 4);       // slab pinned to XCD (matches f1)
  const int bn = idx & 15;
  const int row0 = bm * 64, col0 = bn * 32;
  const int r16 = lane & 15, q = lane >> 4;
  const int srow = lane >> 2;
  const int scol = (((lane & 3) ^ ((srow >> 1) & 3))) * 8;
  const int cqa = (q ^ ((r16 >> 1) & 3)) * 8;

  if (bn == 0 && tid < 64) {
    int b = row0 + tid;
    float c = 0.5f * (div0[b] + div1[b]);
    c = fminf(fmaxf(c, -100.f), 100.f);
    lp[b] -= wdt * c;
    div0[b] = 0.f; div1[b] = 0.f;
  }

  f32x4 acc[2];
  acc[0] = (f32x4){0,0,0,0}; acc[1] = (f32x4){0,0,0,0};

  const size_t arow = (size_t)(row0 + wave * 16 + srow) * 1024 + scol;
  const size_t brow = (size_t)(col0 + (wave & 1) * 16 + srow) * 1024 + scol;
  auto stage = [&](int kt, int buf) {
    u16* b = &S[buf][0];
    __builtin_amdgcn_global_load_lds((ga_u32*)(hbuf + arow + kt), (ls_u32*)(b + wave * 512), 16, 0, 0);
    if (wave < 2)
      __builtin_amdgcn_global_load_lds((ga_u32*)(W2T + brow + kt), (ls_u32*)(b + 4096 + wave * 512), 16, 0, 0);
  };
  stage(0, 0);
  for (int it = 0; it < 32; ++it) {
    const int buf = it & 1;
    __syncthreads();
    if (it + 1 < 32) stage((it + 1) * 32, buf ^ 1);
    const u16* b = &S[buf][0];
    s16x8 af  = *(const s16x8*)(b + (wave * 16 + r16) * 32 + cqa);
    s16x8 bf0 = *(const s16x8*)(b + 4096 + r16 * 32 + cqa);
    s16x8 bf1 = *(const s16x8*)(b + 4096 + (16 + r16) * 32 + cqa);
    acc[0] = __builtin_amdgcn_mfma_f32_16x16x32_bf16(af, bf0, acc[0], 0, 0, 0);
    acc[1] = __builtin_amdgcn_mfma_f32_16x16x32_bf16(af, bf1, acc[1], 0, 0, 0);
  }

#pragma unroll
  for (int j = 0; j < 2; ++j) {
    const int gcol = col0 + j * 16 + r16;
    const float cb = b2v[gcol];
    const int rbase = row0 + wave * 16 + q * 4;
#pragma unroll
    for (int r = 0; r < 4; ++r) {
      const size_t idx2 = (size_t)(rbase + r) * D_N + gcol;
      const float f = acc[j][r] + cb;
      if (ST == 0) {
        ACC[idx2] = dt * 0.125f * f;
        T[idx2]   = dt * f;
        zin[idx2] = f2bf(z[idx2] + dt * f * (1.f / 3.f));
      } else if (ST == 1) {
        float t_ = T[idx2];
        ACC[idx2] += 0.375f * dt * f;
        zin[idx2] = f2bf(z[idx2] + dt * f - t_ * (1.f / 3.f));
        T[idx2]   = t_ - dt * f;
      } else if (ST == 2) {
        ACC[idx2] += 0.375f * dt * f;
        zin[idx2] = f2bf(z[idx2] + T[idx2] + dt * f);
      } else {
        float zn = z[idx2] + ACC[idx2] + dt * 0.125f * f;
        z[idx2]   = zn;
        zin[idx2] = f2bf(zn);
      }
    }
  }

  // Generate next stage's bf16 e for this block's share of the slab (XCD-local).
  if (ebfnext) {
    const int pr = tid >> 7, u = tid & 127;
    const uint32_t p0 = (uint32_t)(bm * 32768 + bn * 2048 + u * 16);
    const uint32_t k0 = keys[(sg + 1) * 4 + pr * 2], k1 = keys[(sg + 1) * 4 + pr * 2 + 1];
    uint4* dst = (uint4*)(ebfnext + (size_t)pr * BD + (size_t)p0);
#pragma unroll
    for (int g = 0; g < 2; ++g) {
      uint32_t pk[4];
#pragma unroll
      for (int h = 0; h < 4; ++h) {
        uint32_t c0 = p0 + g * 8 + h * 2;
        U2 r0 = tf2x32(k0, k1, 0u, c0);
        U2 r1 = tf2x32(k0, k1, 0u, c0 + 1u);
        pk[h] = (((r0.x ^ r0.y) & 1u) ? 0x3F80u : 0xBF80u) |
                (((r1.x ^ r1.y) & 1u) ? 0x3F800000u : 0xBF800000u);
      }
      uint4 v; v.x = pk[0]; v.y = pk[1]; v.z = pk[2]; v.w = pk[3];
      dst[g] = v;
    }
  }
}

// out = [rep (f32, BxD) ; logprob (f32, B)] — XCD-affine row mapping.
__global__ void k_out(const float* __restrict__ z, const float* __restrict__ lp,
                      float* __restrict__ out) {
  const int xcd = blockIdx.x & 7, idx = blockIdx.x >> 3;    // 2048 blocks
  const int b = (xcd * 4 + (idx >> 6)) * 64 + (idx & 63);
  int t = threadIdx.x;
  const float* zr = z + (size_t)b * D_N;
  float ss = 0.f;
  for (int d = t; d < D_N; d += 256) {
    float v = zr[d];
    out[(size_t)b * D_N + d] = v;
    ss += v * v;
  }
  for (int off = 32; off > 0; off >>= 1) ss += __shfl_down(ss, off);
  __shared__ float red[4];
  if ((t & 63) == 0) red[t >> 6] = ss;
  __syncthreads();
  if (t == 0) out[(size_t)BD + b] = -0.5f * (red[0] + red[1] + red[2] + red[3]) + lp[b];
}

extern "C" void kernel_launch(void* const* d_in, const int* in_sizes, int n_in,
                              void* d_out, int out_size, void* d_ws, size_t ws_size,
                              hipStream_t stream) {
  const float* x   = (const float*)d_in[0];
  const float* W1  = (const float*)d_in[1];
  const float* b1  = (const float*)d_in[2];
  const float* tw1 = (const float*)d_in[3];
  const float* W2  = (const float*)d_in[4];
  const float* b2  = (const float*)d_in[5];
  float* outp = (float*)d_out;

  const size_t NEEDED = (size_t)40 << 20;
  if (ws_size < NEEDED) {
    k_sentinel<<<(BD + B_N + 255) / 256, 256, 0, stream>>>(outp, BD + B_N);
    return;
  }
  char* w = (char*)d_ws;
  auto carve = [&](size_t bytes) { char* p = w; w += (bytes + 255) & ~(size_t)255; return p; };
  uint32_t* keys = (uint32_t*)carve(144 * sizeof(uint32_t));
  u16* ebf   = (u16*)carve((size_t)2 * 2 * BD * 2);               // 8 MB: 2-slot bf16 e ring
  float* z   = (float*)carve((size_t)BD * 4);
  float* ACC = (float*)carve((size_t)BD * 4);
  float* T   = (float*)carve((size_t)BD * 4);
  u16* zin   = (u16*)carve((size_t)BD * 2);
  u16* hbuf  = (u16*)carve((size_t)B_N * H_N * 2);
  u16* W1T   = (u16*)carve((size_t)H_N * D_N * 2);
  u16* W2b   = (u16*)carve((size_t)H_N * D_N * 2);
  u16* W2T   = (u16*)carve((size_t)D_N * H_N * 2);
  float* lp   = (float*)carve((size_t)B_N * 4);
  float* div0 = (float*)carve((size_t)B_N * 4);
  float* div1 = (float*)carve((size_t)B_N * 4);

  k_keysched<<<1, 1, 0, stream>>>(keys);
  k_egen1<<<256, 256, 0, stream>>>(ebf, keys);      // stage 0 -> slot 0
  k_init<<<BD / 256, 256, 0, stream>>>(x, z, zin, lp, div0, div1);
  k_cvtT<<<(D_N * H_N) / 256, 256, 0, stream>>>(W1, W1T, D_N, H_N);
  k_cvt <<<(H_N * D_N) / 256, 256, 0, stream>>>(W2, W2b, H_N * D_N);
  k_cvtT<<<(H_N * D_N) / 256, 256, 0, stream>>>(W2, W2T, H_N, D_N);

  const int gF1 = (B_N / 64) * (H_N / 64);   // 512
  const int gF3 = (B_N / 64) * (D_N / 32);   // 512

  for (int s = 0; s < 9; ++s) {
    float t0 = (float)s / 9.0f;
    float t1 = (float)(s + 1) / 9.0f;
    float dt = t1 - t0;
    float tst[4] = { t0, t0 + dt / 3.0f, t0 + dt * 2.0f / 3.0f, t1 };
    float wts[4] = { 1.f, 3.f, 3.f, 1.f };
    for (int st = 0; st < 4; ++st) {
      const int sg = s * 4 + st;
      const u16* e0g = ebf + (size_t)(sg & 1) * (2 * (size_t)BD);
      const u16* e1g = e0g + BD;
      u16* enext = (sg + 1 < 36) ? ebf + (size_t)((sg + 1) & 1) * (2 * (size_t)BD) : nullptr;
      k_f1<<<gF1, 256, 0, stream>>>(zin, e0g, e1g, W1T, W2b, b1, tw1, tst[st], hbuf, div0, div1);
      const float wdt = dt * 0.125f * wts[st];
      if (st == 0)      k_f3<0><<<gF3, 256, 0, stream>>>(hbuf, W2T, b2, z, ACC, T, zin, dt, lp, div0, div1, wdt, keys, sg, enext);
      else if (st == 1) k_f3<1><<<gF3, 256, 0, stream>>>(hbuf, W2T, b2, z, ACC, T, zin, dt, lp, div0, div1, wdt, keys, sg, enext);
      else if (st == 2) k_f3<2><<<gF3, 256, 0, stream>>>(hbuf, W2T, b2, z, ACC, T, zin, dt, lp, div0, div1, wdt, keys, sg, enext);
      else              k_f3<3><<<gF3, 256, 0, stream>>>(hbuf, W2T, b2, z, ACC, T, zin, dt, lp, div0, div1, wdt, keys, sg, enext);
    }
  }
  k_out<<<B_N, 256, 0, stream>>>(z, lp, outp);
}